// Round 2
// 1045.113 us; speedup vs baseline: 1.1623x; 1.1623x over previous
//
#include <hip/hip_runtime.h>
#include <hip/hip_bf16.h>

#define N_USER 60000
#define N_ITEM 120000
#define NTOT   180000
#define NNZ_ADJ 3600000
#define NNZ_UG   960000
#define NNZ_IG  1920000

#define RSB     2048        // rows per super-bin
#define NSB_ADJ ((NTOT  + RSB - 1) / RSB)   // 88
#define NSB_UG  ((N_USER+ RSB - 1) / RSB)   // 30
#define NSB_IG  ((N_ITEM+ RSB - 1) / RSB)   // 59
#define CAPA_SB 43008       // mean 40960 + 10 sigma
#define CAPU_SB 34816
#define CAPI_SB 34816
#define CHUNK   4096

typedef __hip_bfloat16 bf16;
typedef __attribute__((ext_vector_type(8))) short bf16x8;   // one MFMA A/B fragment
typedef __attribute__((ext_vector_type(4))) float f32x4;    // one MFMA C/D fragment

// load float element i from input tensor of unknown dtype: flag=1 -> fp32, 0 -> bf16
__device__ __forceinline__ float ldf(const void* p, long i, int f) {
    return f ? ((const float*)p)[i] : __bfloat162float(((const bf16*)p)[i]);
}

// pack two fp32 -> one uint holding 2 bf16
__device__ __forceinline__ unsigned pk2(float a, float b) {
    unsigned short lo = __bfloat16_as_ushort(__float2bfloat16(a));
    unsigned short hi = __bfloat16_as_ushort(__float2bfloat16(b));
    return (unsigned)lo | ((unsigned)hi << 16);
}

// ---------------- dtype detector (adj_vals >= 0 -> bf16 words have bit15==0) ----
__global__ void k_detect(const void* __restrict__ vals, int* __restrict__ flag) {
    if (threadIdx.x == 0 && blockIdx.x == 0) {
        const unsigned short* w = (const unsigned short*)vals;
        int cnt = 0;
        for (int i = 0; i < 512; i += 2) cnt += (w[i] >> 15) & 1;
        *flag = (cnt > 16) ? 1 : 0;
    }
}

// ---------------- cast user/item emb -> ego bf16 ----------------
__global__ __launch_bounds__(256) void k_cast16(const void* __restrict__ ue,
                                                const void* __restrict__ ie,
                                                bf16* __restrict__ ego16,
                                                const int* __restrict__ flag) {
    int f = *flag;
    long i = (long)blockIdx.x * 256 + threadIdx.x;   // NTOT*64 = 11,520,000
    const long uN = (long)N_USER * 64;
    if (i < (long)NTOT * 64) {
        float v = (i < uN) ? ldf(ue, i, f) : ldf(ie, i - uN, f);
        ego16[i] = __float2bfloat16(v);
    }
}

// ================= two-level binned build =================
__global__ __launch_bounds__(256) void k_initpos(int* __restrict__ sbpos, int nsb, int cap) {
    int i = blockIdx.x * 256 + threadIdx.x;
    if (i < nsb) sbpos[i * 16] = i * cap;
}

// L1: partition edges into <=88 super-bins (2048 rows each).
// Record: {rl(11b)<<18 | col(18b), val_f32}
__global__ __launch_bounds__(256) void k_part(const int* __restrict__ rows,
                                              const int* __restrict__ cols,
                                              const void* __restrict__ vals,
                                              uint2* __restrict__ rec,
                                              int* __restrict__ sbpos,
                                              int nnz,
                                              const int* __restrict__ flag) {
    __shared__ int lcnt[96];
    __shared__ int lbase[96];
    int f = *flag;
    int t = threadIdx.x;
    int base = blockIdx.x * CHUNK;
    if (t < 96) lcnt[t] = 0;
    __syncthreads();
    for (int k = 0; k < CHUNK / 256; k++) {
        int e = base + k * 256 + t;
        if (e < nnz) atomicAdd(&lcnt[rows[e] >> 11], 1);
    }
    __syncthreads();
    if (t < 96) {
        int c = lcnt[t];
        lbase[t] = c ? atomicAdd(&sbpos[t * 16], c) : 0;
        lcnt[t] = 0;
    }
    __syncthreads();
    for (int k = 0; k < CHUNK / 256; k++) {
        int e = base + k * 256 + t;
        if (e < nnz) {
            int r = rows[e];
            int sb = r >> 11;
            int o = atomicAdd(&lcnt[sb], 1);
            unsigned meta = ((unsigned)(r & 2047) << 18) | (unsigned)cols[e];
            rec[lbase[sb] + o] = make_uint2(meta, __float_as_uint(ldf(vals, e, f)));
        }
    }
}

// L2: per-super-bin counting sort into row order; emits absolute [rstart, rend).
__global__ __launch_bounds__(1024) void k_sortsb(const uint2* __restrict__ rec,
                                                 uint2* __restrict__ rec2,
                                                 int* __restrict__ rstart,
                                                 int* __restrict__ rend,
                                                 const int* __restrict__ sbpos,
                                                 int cap, int n_rows) {
    __shared__ int cnt[RSB];
    __shared__ int pos[RSB];
    __shared__ int carry;
    int b = blockIdx.x, t = threadIdx.x;
    int s = b * cap;
    int e = sbpos[b * 16];           // final fill cursor
    cnt[t] = 0; cnt[t + 1024] = 0;
    if (t == 0) carry = 0;
    __syncthreads();
    for (int j = s + t; j < e; j += 1024)
        atomicAdd(&cnt[rec[j].x >> 18], 1);
    __syncthreads();
    for (int tile = 0; tile < 2; tile++) {
        int i = tile * 1024 + t;
        int v = cnt[i];
        pos[i] = v;
        __syncthreads();
        for (int d = 1; d < 1024; d <<= 1) {
            int w = (t >= d) ? pos[i - d] : 0;
            __syncthreads();
            if (t >= d) pos[i] += w;
            __syncthreads();
        }
        int inc = pos[i];            // inclusive within tile
        int ex  = carry + inc - v;   // exclusive global
        __syncthreads();
        pos[i] = ex;
        if (t == 1023) carry += inc;
        __syncthreads();
    }
    int row0 = b * RSB;
    for (int i = t; i < RSB; i += 1024) {
        int row = row0 + i;
        if (row < n_rows) {
            rstart[row] = s + pos[i];
            rend[row]   = s + pos[i] + cnt[i];
        }
    }
    __syncthreads();
    for (int j = s + t; j < e; j += 1024) {
        uint2 r = rec[j];
        int o = atomicAdd(&pos[r.x >> 18], 1);
        rec2[s + o] = r;
    }
}

// ================= CSR SpMM, bf16 x: one row per 8-lane octet =================
// MODE 1: out = bf16 S row (stride 64)
// MODE 2: out = interleaved bf16 [S(8)|P(8)]x8 row (stride 128), P = Ein .* S
template <int MODE>
__global__ __launch_bounds__(256) void k_spmm_bf(const int* __restrict__ rstart,
                                                 const int* __restrict__ rend,
                                                 const uint2* __restrict__ rec,
                                                 const bf16* __restrict__ x,
                                                 bf16* __restrict__ out,
                                                 const bf16* __restrict__ Ein,
                                                 int n_rows) {
    int row = blockIdx.x * 32 + (threadIdx.x >> 3);
    int p = threadIdx.x & 7;
    if (row >= n_rows) return;
    int s = rstart[row], e = rend[row];
    const uint4* xb = (const uint4*)x;   // 8 bf16 per uint4
    float a[8];
#pragma unroll
    for (int i = 0; i < 8; i++) a[i] = 0.0f;
    for (int j = s; j < e; j++) {
        uint2 r = rec[j];
        int col = r.x & 0x3FFFF;
        float v = __uint_as_float(r.y);
        uint4 q = xb[(long)col * 8 + p];
        a[0] += v * __uint_as_float(q.x << 16);
        a[1] += v * __uint_as_float(q.x & 0xFFFF0000u);
        a[2] += v * __uint_as_float(q.y << 16);
        a[3] += v * __uint_as_float(q.y & 0xFFFF0000u);
        a[4] += v * __uint_as_float(q.z << 16);
        a[5] += v * __uint_as_float(q.z & 0xFFFF0000u);
        a[6] += v * __uint_as_float(q.w << 16);
        a[7] += v * __uint_as_float(q.w & 0xFFFF0000u);
    }
    if (MODE == 1) {
        *(uint4*)(out + (long)row * 64 + p * 8) =
            make_uint4(pk2(a[0], a[1]), pk2(a[2], a[3]),
                       pk2(a[4], a[5]), pk2(a[6], a[7]));
    } else {
        uint4 eq = *(const uint4*)(Ein + (long)row * 64 + p * 8);
        float pr[8];
        pr[0] = a[0] * __uint_as_float(eq.x << 16);
        pr[1] = a[1] * __uint_as_float(eq.x & 0xFFFF0000u);
        pr[2] = a[2] * __uint_as_float(eq.y << 16);
        pr[3] = a[3] * __uint_as_float(eq.y & 0xFFFF0000u);
        pr[4] = a[4] * __uint_as_float(eq.z << 16);
        pr[5] = a[5] * __uint_as_float(eq.z & 0xFFFF0000u);
        pr[6] = a[6] * __uint_as_float(eq.w << 16);
        pr[7] = a[7] * __uint_as_float(eq.w & 0xFFFF0000u);
        bf16* ob = out + (long)row * 128 + p * 16;
        *(uint4*)ob = make_uint4(pk2(a[0], a[1]), pk2(a[2], a[3]),
                                 pk2(a[4], a[5]), pk2(a[6], a[7]));
        *(uint4*)(ob + 8) = make_uint4(pk2(pr[0], pr[1]), pk2(pr[2], pr[3]),
                                       pk2(pr[4], pr[5]), pk2(pr[6], pr[7]));
    }
}

// ---------------- Y[M,64] = act(X16[M,64] @ W[64,64] + b) -> bf16 --------------
// MFMA version: mfma_f32_16x16x32_bf16, weights split bf16 hi+lo for fp32-like
// accuracy (weight error ~2^-17). Wt = W^T in LDS (B^T fragment layout, +8 pad).
// A frag: row = lane&15, k = 8*(lane>>4)+e (contiguous 16B per lane from X row).
// D frag: col = lane&15, row = 4*(lane>>4)+reg  [verified mapping].
template <int ACT>
__global__ __launch_bounds__(256) void k_gemm64(const bf16* __restrict__ X,
                                                const void* __restrict__ W,
                                                const void* __restrict__ b,
                                                bf16* __restrict__ Y, int M,
                                                const int* __restrict__ flag) {
    __shared__ bf16 WtH[64][72];
    __shared__ bf16 WtL[64][72];
    __shared__ float bl[64];
    int f = *flag;
    int tid = threadIdx.x;
    for (int idx = tid; idx < 4096; idx += 256) {
        int n = idx >> 6, kk = idx & 63;
        float v = ldf(W, (long)kk * 64 + n, f);
        bf16 h = __float2bfloat16(v);
        WtH[n][kk] = h;
        WtL[n][kk] = __float2bfloat16(v - __bfloat162float(h));
    }
    if (tid < 64) bl[tid] = ldf(b, tid, f);
    __syncthreads();

    int l  = tid & 63;
    int lr = l & 15;      // A row / D col within tile
    int lk = l >> 4;      // k sub-block / D row group

    bf16x8 bh[2][4], bb[2][4];
#pragma unroll
    for (int kt = 0; kt < 2; kt++)
#pragma unroll
        for (int ct = 0; ct < 4; ct++) {
            int n  = ct * 16 + lr;
            int ko = kt * 32 + lk * 8;
            bh[kt][ct] = *(const bf16x8*)&WtH[n][ko];
            bb[kt][ct] = *(const bf16x8*)&WtL[n][ko];
        }

    int nt  = M >> 4;                       // M is a multiple of 16
    int wid = blockIdx.x * 4 + (tid >> 6);
    int nw  = gridDim.x * 4;

    for (int t = wid; t < nt; t += nw) {
        const bf16* Ap = X + (long)(t * 16 + lr) * 64 + lk * 8;
        bf16x8 a[2];
#pragma unroll
        for (int kt = 0; kt < 2; kt++) a[kt] = *(const bf16x8*)(Ap + kt * 32);

        f32x4 acc[4];
#pragma unroll
        for (int ct = 0; ct < 4; ct++) {
            float bv = bl[ct * 16 + lr];
            acc[ct] = (f32x4){bv, bv, bv, bv};
        }
#pragma unroll
        for (int kt = 0; kt < 2; kt++)
#pragma unroll
            for (int ct = 0; ct < 4; ct++) {
                acc[ct] = __builtin_amdgcn_mfma_f32_16x16x32_bf16(a[kt], bh[kt][ct], acc[ct], 0, 0, 0);
                acc[ct] = __builtin_amdgcn_mfma_f32_16x16x32_bf16(a[kt], bb[kt][ct], acc[ct], 0, 0, 0);
            }

#pragma unroll
        for (int r = 0; r < 4; r++) {
            float v0 = acc[0][r], v1 = acc[1][r], v2 = acc[2][r], v3 = acc[3][r];
            if (ACT == 2) {
                v0 = fmaxf(v0, 0.0f); v1 = fmaxf(v1, 0.0f);
                v2 = fmaxf(v2, 0.0f); v3 = fmaxf(v3, 0.0f);
            } else {
                v0 = (v0 > 0.0f) ? v0 : (expf(v0) - 1.0f);
                v1 = (v1 > 0.0f) ? v1 : (expf(v1) - 1.0f);
                v2 = (v2 > 0.0f) ? v2 : (expf(v2) - 1.0f);
                v3 = (v3 > 0.0f) ? v3 : (expf(v3) - 1.0f);
            }
            long ob = (long)(t * 16 + lk * 4 + r) * 64 + lr;
            Y[ob]      = __float2bfloat16(v0);
            Y[ob + 16] = __float2bfloat16(v1);
            Y[ob + 32] = __float2bfloat16(v2);
            Y[ob + 48] = __float2bfloat16(v3);
        }
    }
}

// ---------------- fused NGCF layer + l2norm; ego bf16 updated IN PLACE --------
// MFMA K=128 bf16 GEMM on interleaved SP rows ([S8|P8]x8); Wcat = interleaved
// stack of Wgc/Wbi rows, transposed into LDS as B^T, split bf16 hi+lo.
// Epilogue: leaky-relu + row l2norm via shfl_xor 1/2/4/8 over the 16-lane
// column group (lane holds cols ct*16 + (lane&15), rows 4*(lane>>4)+r).
__global__ __launch_bounds__(256) void k_layer(const bf16* __restrict__ SP,
                                               bf16* __restrict__ E16,
                                               const void* __restrict__ Wgc,
                                               const void* __restrict__ bgc,
                                               const void* __restrict__ Wbi,
                                               const void* __restrict__ bbi,
                                               long woff, long boff,
                                               bf16* __restrict__ nm, int M,
                                               const int* __restrict__ flag) {
    __shared__ bf16 WtH[64][136];
    __shared__ bf16 WtL[64][136];
    __shared__ float bl[64];
    int f = *flag;
    int tid = threadIdx.x;
    // Wcat[16g+j] = W1[8g+j]  (j<8),  Wcat[16g+8+j] = W2[8g+j]  -- matches SP interleave
    for (int idx = tid; idx < 8192; idx += 256) {
        int n = idx >> 7, kk = idx & 127;
        int g = kk >> 4, j = kk & 15;
        float v = (j < 8) ? ldf(Wgc, woff + (long)(8 * g + j) * 64 + n, f)
                          : ldf(Wbi, woff + (long)(8 * g + j - 8) * 64 + n, f);
        bf16 h = __float2bfloat16(v);
        WtH[n][kk] = h;
        WtL[n][kk] = __float2bfloat16(v - __bfloat162float(h));
    }
    if (tid < 64) bl[tid] = ldf(bgc, boff + tid, f) + ldf(bbi, boff + tid, f);
    __syncthreads();

    int l  = tid & 63;
    int lr = l & 15;
    int lk = l >> 4;

    bf16x8 bh[4][4], bb[4][4];
#pragma unroll
    for (int kt = 0; kt < 4; kt++)
#pragma unroll
        for (int ct = 0; ct < 4; ct++) {
            int n  = ct * 16 + lr;
            int ko = kt * 32 + lk * 8;
            bh[kt][ct] = *(const bf16x8*)&WtH[n][ko];
            bb[kt][ct] = *(const bf16x8*)&WtL[n][ko];
        }

    int nt  = M >> 4;                 // 11250 for NTOT
    int wid = blockIdx.x * 4 + (tid >> 6);
    int nw  = gridDim.x * 4;

    for (int t = wid; t < nt; t += nw) {
        const bf16* Ap = SP + (long)(t * 16 + lr) * 128 + lk * 8;
        bf16x8 a[4];
#pragma unroll
        for (int kt = 0; kt < 4; kt++) a[kt] = *(const bf16x8*)(Ap + kt * 32);

        f32x4 acc[4];
#pragma unroll
        for (int ct = 0; ct < 4; ct++) {
            float bv = bl[ct * 16 + lr];
            acc[ct] = (f32x4){bv, bv, bv, bv};
        }
#pragma unroll
        for (int kt = 0; kt < 4; kt++)
#pragma unroll
            for (int ct = 0; ct < 4; ct++) {
                acc[ct] = __builtin_amdgcn_mfma_f32_16x16x32_bf16(a[kt], bh[kt][ct], acc[ct], 0, 0, 0);
                acc[ct] = __builtin_amdgcn_mfma_f32_16x16x32_bf16(a[kt], bb[kt][ct], acc[ct], 0, 0, 0);
            }

#pragma unroll
        for (int r = 0; r < 4; r++) {
            float v0 = acc[0][r], v1 = acc[1][r], v2 = acc[2][r], v3 = acc[3][r];
            v0 = (v0 > 0.0f) ? v0 : 0.2f * v0;
            v1 = (v1 > 0.0f) ? v1 : 0.2f * v1;
            v2 = (v2 > 0.0f) ? v2 : 0.2f * v2;
            v3 = (v3 > 0.0f) ? v3 : 0.2f * v3;
            float ss = v0 * v0 + v1 * v1 + v2 * v2 + v3 * v3;
            ss += __shfl_xor(ss, 1, 64);    // reduce over the 16-lane column group
            ss += __shfl_xor(ss, 2, 64);
            ss += __shfl_xor(ss, 4, 64);
            ss += __shfl_xor(ss, 8, 64);
            float sc2 = 1.0f / fmaxf(sqrtf(ss), 1e-12f);
            long ob = (long)(t * 16 + lk * 4 + r) * 64 + lr;
            E16[ob]      = __float2bfloat16(v0);
            E16[ob + 16] = __float2bfloat16(v1);
            E16[ob + 32] = __float2bfloat16(v2);
            E16[ob + 48] = __float2bfloat16(v3);
            nm[ob]       = __float2bfloat16(v0 * sc2);
            nm[ob + 16]  = __float2bfloat16(v1 * sc2);
            nm[ob + 32]  = __float2bfloat16(v2 * sc2);
            nm[ob + 48]  = __float2bfloat16(v3 * sc2);
        }
    }
}

// ---------------- final gather into output ----------------
__global__ __launch_bounds__(64) void k_gather(const int* __restrict__ users,
                                               const int* __restrict__ pos,
                                               const int* __restrict__ neg,
                                               const void* __restrict__ ue,
                                               const void* __restrict__ ie,
                                               const bf16* __restrict__ n1,
                                               const bf16* __restrict__ n2,
                                               const bf16* __restrict__ n3,
                                               const bf16* __restrict__ uh,
                                               const bf16* __restrict__ ih,
                                               void* __restrict__ out,
                                               const int* __restrict__ flag) {
    int f = *flag;
    int b = blockIdx.x;           // 0..12287: [users | pos | neg] x 4096
    int which = b >> 12;
    int s = b & 4095;
    int lane = threadIdx.x;       // 64
    long ebase, nbase;
    const void* e0;
    const bf16* hh;
    if (which == 0) {
        int r = users[s];
        e0 = ue; ebase = (long)r * 64;
        hh = uh + (long)r * 64;
        nbase = (long)r * 64;
    } else {
        int r = (which == 1) ? pos[s] : neg[s];
        e0 = ie; ebase = (long)r * 64;
        hh = ih + (long)r * 64;
        nbase = (long)(N_USER + r) * 64;
    }
    float o0 = ldf(e0, ebase + lane, f);
    float o1 = __bfloat162float(n1[nbase + lane]);
    float o2 = __bfloat162float(n2[nbase + lane]);
    float o3 = __bfloat162float(n3[nbase + lane]);
    float o4 = __bfloat162float(hh[lane]);
    long ob = (long)b * 320;
    if (f) {
        float* o = (float*)out + ob;
        o[lane] = o0; o[64 + lane] = o1; o[128 + lane] = o2;
        o[192 + lane] = o3; o[256 + lane] = o4;
    } else {
        bf16* o = (bf16*)out + ob;
        o[lane]       = __float2bfloat16(o0);
        o[64 + lane]  = __float2bfloat16(o1);
        o[128 + lane] = __float2bfloat16(o2);
        o[192 + lane] = __float2bfloat16(o3);
        o[256 + lane] = __float2bfloat16(o4);
    }
}

// host-side helper: two-level build of row-sorted packed records for one graph
static void build_graph(const int* rows, const int* cols, const void* vals,
                        int nnz, int nsb, int cap, int n_rows,
                        int* sbpos, uint2* recTmp, uint2* rec2,
                        int* rstart, int* rend,
                        const int* FLAG, hipStream_t stream) {
    k_initpos<<<1, 256, 0, stream>>>(sbpos, nsb, cap);
    k_part<<<(nnz + CHUNK - 1) / CHUNK, 256, 0, stream>>>(rows, cols, vals, recTmp, sbpos, nnz, FLAG);
    k_sortsb<<<nsb, 1024, 0, stream>>>(recTmp, rec2, rstart, rend, sbpos, cap, n_rows);
}

extern "C" void kernel_launch(void* const* d_in, const int* in_sizes, int n_in,
                              void* d_out, int out_size, void* d_ws, size_t ws_size,
                              hipStream_t stream) {
    const int* users = (const int*)d_in[0];
    const int* pos   = (const int*)d_in[1];
    const int* neg   = (const int*)d_in[2];
    const int* adj_r = (const int*)d_in[3];
    const int* adj_c = (const int*)d_in[4];
    const void* adj_v = d_in[5];
    const int* ug_r  = (const int*)d_in[6];
    const int* ug_c  = (const int*)d_in[7];
    const void* ug_v = d_in[8];
    const int* ig_r  = (const int*)d_in[9];
    const int* ig_c  = (const int*)d_in[10];
    const void* ig_v = d_in[11];
    const void* ue   = d_in[12];
    const void* ie   = d_in[13];
    const void* Wgc  = d_in[14];
    const void* bgc  = d_in[15];
    const void* Wbi  = d_in[16];
    const void* bbi  = d_in[17];
    const void* Wu0  = d_in[18];
    const void* bu0  = d_in[19];
    const void* Wu1  = d_in[20];
    const void* bu1  = d_in[21];
    const void* Wi0  = d_in[22];
    const void* bi0  = d_in[23];
    const void* Wi1  = d_in[24];
    const void* bi1  = d_in[25];

    char* ws = (char*)d_ws;
    int*   FLAG  = (int*)(ws + 0);                       // 256 B
    bf16*  SP16A = (bf16*)(ws + 256);                    // NTOT*128*2 = 46,080,000
    bf16*  S16T  = (bf16*)(ws + 46080256L);              // N_ITEM*64*2 = 15,360,000
    bf16*  ego16 = (bf16*)(ws + 61440256L);              // 23,040,000
    bf16*  UH    = (bf16*)(ws + 84480256L);              //  7,680,000
    bf16*  IH    = (bf16*)(ws + 92160256L);              // 15,360,000
    bf16*  NM1   = (bf16*)(ws + 107520256L);             // 23,040,000
    bf16*  NM2   = (bf16*)(ws + 130560256L);             // 23,040,000
    bf16*  NM3   = (bf16*)(ws + 153600256L);             // 23,040,000
    // T2 (bf16, <=15.36 MB) aliases NM2: dead before layer k=1 writes NM2
    bf16*  T2    = (bf16*)(ws + 130560256L);
    // recTmp aliases SP16A: builds finish before first adj spmm writes SP16A
    uint2* recTmp = (uint2*)(ws + 256);
    uint2* rec2A = (uint2*)(ws + 176640256L);            // 30,277,632
    uint2* rec2U = (uint2*)(ws + 206917888L);            //  8,355,840
    uint2* rec2I = (uint2*)(ws + 215273728L);            // 16,433,152
    int* rstartA = (int*)(ws + 231706880L);              //    720,000
    int* rendA   = (int*)(ws + 232426880L);              //    720,000
    int* rstartU = (int*)(ws + 233146880L);              //    240,000
    int* rendU   = (int*)(ws + 233386880L);              //    240,000
    int* rstartI = (int*)(ws + 233626880L);              //    480,000
    int* rendI   = (int*)(ws + 234106880L);              //    480,000
    int* sbpos   = (int*)(ws + 234586880L);              //      6,144
                                                         // end 234,593,024 (< 261,120,256 proven)

    k_detect<<<1, 64, 0, stream>>>(adj_v, FLAG);
    k_cast16<<<45000, 256, 0, stream>>>(ue, ie, ego16, FLAG);

    // ---- two-level build of row-sorted packed records (recTmp aliases SP16A) ----
    build_graph(ug_r,  ug_c,  ug_v,  NNZ_UG,  NSB_UG,  CAPU_SB, N_USER,
                sbpos, recTmp, rec2U, rstartU, rendU, FLAG, stream);
    build_graph(ig_r,  ig_c,  ig_v,  NNZ_IG,  NSB_IG,  CAPI_SB, N_ITEM,
                sbpos, recTmp, rec2I, rstartI, rendI, FLAG, stream);
    build_graph(adj_r, adj_c, adj_v, NNZ_ADJ, NSB_ADJ, CAPA_SB, NTOT,
                sbpos, recTmp, rec2A, rstartA, rendA, FLAG, stream);

    // ---- user MLP branch (bf16 S throughout) ----
    int gu = (N_USER / 16 + 7) / 8;     // ~2 row-tiles per wave
    int gi = (N_ITEM / 16 + 7) / 8;
    k_spmm_bf<1><<<(N_USER + 31) / 32, 256, 0, stream>>>(rstartU, rendU, rec2U, ego16, S16T, nullptr, N_USER);
    k_gemm64<1><<<gu, 256, 0, stream>>>(S16T, Wu0, bu0, T2, N_USER, FLAG);
    k_spmm_bf<1><<<(N_USER + 31) / 32, 256, 0, stream>>>(rstartU, rendU, rec2U, T2, S16T, nullptr, N_USER);
    k_gemm64<2><<<gu, 256, 0, stream>>>(S16T, Wu1, bu1, UH, N_USER, FLAG);

    // ---- item MLP branch ----
    const bf16* ego16I = ego16 + (size_t)N_USER * 64;
    k_spmm_bf<1><<<(N_ITEM + 31) / 32, 256, 0, stream>>>(rstartI, rendI, rec2I, ego16I, S16T, nullptr, N_ITEM);
    k_gemm64<1><<<gi, 256, 0, stream>>>(S16T, Wi0, bi0, T2, N_ITEM, FLAG);
    k_spmm_bf<1><<<(N_ITEM + 31) / 32, 256, 0, stream>>>(rstartI, rendI, rec2I, T2, S16T, nullptr, N_ITEM);
    k_gemm64<2><<<gi, 256, 0, stream>>>(S16T, Wi1, bi1, IH, N_ITEM, FLAG);

    // ---- 3 NGCF layers: spmm emits interleaved [S|P] bf16; layer = MFMA K=128 GEMM ----
    bf16* norms[3] = {NM1, NM2, NM3};
    for (int k = 0; k < 3; k++) {
        k_spmm_bf<2><<<(NTOT + 31) / 32, 256, 0, stream>>>(rstartA, rendA, rec2A, ego16, SP16A, ego16, NTOT);
        // 704 blocks * 4 waves = 2816 waves -> ~4 row-tiles each of 11250
        k_layer<<<704, 256, 0, stream>>>(SP16A, ego16, Wgc, bgc, Wbi, bbi,
                                         (long)k * 4096, (long)k * 64,
                                         norms[k], NTOT, FLAG);
    }

    // ---- output gather ----
    k_gather<<<12288, 64, 0, stream>>>(users, pos, neg, ue, ie, NM1, NM2, NM3, UH, IH,
                                       d_out, FLAG);
}

// Round 3
// 998.086 us; speedup vs baseline: 1.2171x; 1.0471x over previous
//
#include <hip/hip_runtime.h>
#include <hip/hip_bf16.h>

#define N_USER 60000
#define N_ITEM 120000
#define NTOT   180000
#define NNZ_ADJ 3600000
#define NNZ_UG   960000
#define NNZ_IG  1920000

#define RSB     2048        // rows per super-bin
#define NSB_ADJ ((NTOT  + RSB - 1) / RSB)   // 88
#define NSB_UG  ((N_USER+ RSB - 1) / RSB)   // 30
#define NSB_IG  ((N_ITEM+ RSB - 1) / RSB)   // 59
#define CAPA_SB 43008       // mean 40960 + 10 sigma
#define CAPU_SB 34816
#define CAPI_SB 34816
#define CHUNK   4096

typedef __hip_bfloat16 bf16;
typedef __attribute__((ext_vector_type(8))) short bf16x8;   // one MFMA A/B fragment
typedef __attribute__((ext_vector_type(4))) float f32x4;    // one MFMA C/D fragment

// load float element i from input tensor of unknown dtype: flag=1 -> fp32, 0 -> bf16
__device__ __forceinline__ float ldf(const void* p, long i, int f) {
    return f ? ((const float*)p)[i] : __bfloat162float(((const bf16*)p)[i]);
}

// pack two fp32 -> one uint holding 2 bf16
__device__ __forceinline__ unsigned pk2(float a, float b) {
    unsigned short lo = __bfloat16_as_ushort(__float2bfloat16(a));
    unsigned short hi = __bfloat16_as_ushort(__float2bfloat16(b));
    return (unsigned)lo | ((unsigned)hi << 16);
}

// ---------------- dtype detector (adj_vals >= 0 -> bf16 words have bit15==0) ----
__global__ void k_detect(const void* __restrict__ vals, int* __restrict__ flag) {
    if (threadIdx.x == 0 && blockIdx.x == 0) {
        const unsigned short* w = (const unsigned short*)vals;
        int cnt = 0;
        for (int i = 0; i < 512; i += 2) cnt += (w[i] >> 15) & 1;
        *flag = (cnt > 16) ? 1 : 0;
    }
}

// ---------------- cast user/item emb -> ego bf16 ----------------
__global__ __launch_bounds__(256) void k_cast16(const void* __restrict__ ue,
                                                const void* __restrict__ ie,
                                                bf16* __restrict__ ego16,
                                                const int* __restrict__ flag) {
    int f = *flag;
    long i = (long)blockIdx.x * 256 + threadIdx.x;   // NTOT*64 = 11,520,000
    const long uN = (long)N_USER * 64;
    if (i < (long)NTOT * 64) {
        float v = (i < uN) ? ldf(ue, i, f) : ldf(ie, i - uN, f);
        ego16[i] = __float2bfloat16(v);
    }
}

// ================= two-level binned build =================
__global__ __launch_bounds__(256) void k_initpos(int* __restrict__ sbpos, int nsb, int cap) {
    int i = blockIdx.x * 256 + threadIdx.x;
    if (i < nsb) sbpos[i * 16] = i * cap;
}

// L1: partition edges into <=88 super-bins (2048 rows each).
// Record: {rl(11b)<<18 | col(18b), val_f32}
__global__ __launch_bounds__(256) void k_part(const int* __restrict__ rows,
                                              const int* __restrict__ cols,
                                              const void* __restrict__ vals,
                                              uint2* __restrict__ rec,
                                              int* __restrict__ sbpos,
                                              int nnz,
                                              const int* __restrict__ flag) {
    __shared__ int lcnt[96];
    __shared__ int lbase[96];
    int f = *flag;
    int t = threadIdx.x;
    int base = blockIdx.x * CHUNK;
    if (t < 96) lcnt[t] = 0;
    __syncthreads();
    for (int k = 0; k < CHUNK / 256; k++) {
        int e = base + k * 256 + t;
        if (e < nnz) atomicAdd(&lcnt[rows[e] >> 11], 1);
    }
    __syncthreads();
    if (t < 96) {
        int c = lcnt[t];
        lbase[t] = c ? atomicAdd(&sbpos[t * 16], c) : 0;
        lcnt[t] = 0;
    }
    __syncthreads();
    for (int k = 0; k < CHUNK / 256; k++) {
        int e = base + k * 256 + t;
        if (e < nnz) {
            int r = rows[e];
            int sb = r >> 11;
            int o = atomicAdd(&lcnt[sb], 1);
            unsigned meta = ((unsigned)(r & 2047) << 18) | (unsigned)cols[e];
            rec[lbase[sb] + o] = make_uint2(meta, __float_as_uint(ldf(vals, e, f)));
        }
    }
}

// L2: per-super-bin counting sort into row order; emits absolute [rstart, rend).
__global__ __launch_bounds__(1024) void k_sortsb(const uint2* __restrict__ rec,
                                                 uint2* __restrict__ rec2,
                                                 int* __restrict__ rstart,
                                                 int* __restrict__ rend,
                                                 const int* __restrict__ sbpos,
                                                 int cap, int n_rows) {
    __shared__ int cnt[RSB];
    __shared__ int pos[RSB];
    __shared__ int carry;
    int b = blockIdx.x, t = threadIdx.x;
    int s = b * cap;
    int e = sbpos[b * 16];           // final fill cursor
    cnt[t] = 0; cnt[t + 1024] = 0;
    if (t == 0) carry = 0;
    __syncthreads();
    for (int j = s + t; j < e; j += 1024)
        atomicAdd(&cnt[rec[j].x >> 18], 1);
    __syncthreads();
    for (int tile = 0; tile < 2; tile++) {
        int i = tile * 1024 + t;
        int v = cnt[i];
        pos[i] = v;
        __syncthreads();
        for (int d = 1; d < 1024; d <<= 1) {
            int w = (t >= d) ? pos[i - d] : 0;
            __syncthreads();
            if (t >= d) pos[i] += w;
            __syncthreads();
        }
        int inc = pos[i];            // inclusive within tile
        int ex  = carry + inc - v;   // exclusive global
        __syncthreads();
        pos[i] = ex;
        if (t == 1023) carry += inc;
        __syncthreads();
    }
    int row0 = b * RSB;
    for (int i = t; i < RSB; i += 1024) {
        int row = row0 + i;
        if (row < n_rows) {
            rstart[row] = s + pos[i];
            rend[row]   = s + pos[i] + cnt[i];
        }
    }
    __syncthreads();
    for (int j = s + t; j < e; j += 1024) {
        uint2 r = rec[j];
        int o = atomicAdd(&pos[r.x >> 18], 1);
        rec2[s + o] = r;
    }
}

// ================= CSR SpMM, bf16 x: one row per 8-lane octet =================
// MODE 1: out = bf16 S row (stride 64)
// MODE 2: out = interleaved bf16 [S(8)|P(8)]x8 row (stride 128), P = Ein .* S
// Edge loop unrolled x4 with grouped loads: 4 row-gathers in flight per wave
// (round-2 counters: VALUBusy 23%, hbm 41%, VGPR 16 -> latency-bound, no MLP).
// FMA order per accumulator is unchanged (ascending j) -> bit-identical output.
template <int MODE>
__global__ __launch_bounds__(256) void k_spmm_bf(const int* __restrict__ rstart,
                                                 const int* __restrict__ rend,
                                                 const uint2* __restrict__ rec,
                                                 const bf16* __restrict__ x,
                                                 bf16* __restrict__ out,
                                                 const bf16* __restrict__ Ein,
                                                 int n_rows) {
    int row = blockIdx.x * 32 + (threadIdx.x >> 3);
    int p = threadIdx.x & 7;
    if (row >= n_rows) return;
    int s = rstart[row], e = rend[row];
    const uint4* xb = (const uint4*)x;   // 8 bf16 per uint4
    float a[8];
#pragma unroll
    for (int i = 0; i < 8; i++) a[i] = 0.0f;

#define ACC8(q, v)                                   \
    a[0] += (v) * __uint_as_float((q).x << 16);      \
    a[1] += (v) * __uint_as_float((q).x & 0xFFFF0000u); \
    a[2] += (v) * __uint_as_float((q).y << 16);      \
    a[3] += (v) * __uint_as_float((q).y & 0xFFFF0000u); \
    a[4] += (v) * __uint_as_float((q).z << 16);      \
    a[5] += (v) * __uint_as_float((q).z & 0xFFFF0000u); \
    a[6] += (v) * __uint_as_float((q).w << 16);      \
    a[7] += (v) * __uint_as_float((q).w & 0xFFFF0000u);

    int j = s;
    for (; j + 4 <= e; j += 4) {
        uint2 r0 = rec[j];
        uint2 r1 = rec[j + 1];
        uint2 r2 = rec[j + 2];
        uint2 r3 = rec[j + 3];
        uint4 q0 = xb[(long)(r0.x & 0x3FFFF) * 8 + p];
        uint4 q1 = xb[(long)(r1.x & 0x3FFFF) * 8 + p];
        uint4 q2 = xb[(long)(r2.x & 0x3FFFF) * 8 + p];
        uint4 q3 = xb[(long)(r3.x & 0x3FFFF) * 8 + p];
        float v0 = __uint_as_float(r0.y);
        float v1 = __uint_as_float(r1.y);
        float v2 = __uint_as_float(r2.y);
        float v3 = __uint_as_float(r3.y);
        ACC8(q0, v0)
        ACC8(q1, v1)
        ACC8(q2, v2)
        ACC8(q3, v3)
    }
    for (; j < e; j++) {
        uint2 r = rec[j];
        uint4 q = xb[(long)(r.x & 0x3FFFF) * 8 + p];
        float v = __uint_as_float(r.y);
        ACC8(q, v)
    }
#undef ACC8

    if (MODE == 1) {
        *(uint4*)(out + (long)row * 64 + p * 8) =
            make_uint4(pk2(a[0], a[1]), pk2(a[2], a[3]),
                       pk2(a[4], a[5]), pk2(a[6], a[7]));
    } else {
        uint4 eq = *(const uint4*)(Ein + (long)row * 64 + p * 8);
        float pr[8];
        pr[0] = a[0] * __uint_as_float(eq.x << 16);
        pr[1] = a[1] * __uint_as_float(eq.x & 0xFFFF0000u);
        pr[2] = a[2] * __uint_as_float(eq.y << 16);
        pr[3] = a[3] * __uint_as_float(eq.y & 0xFFFF0000u);
        pr[4] = a[4] * __uint_as_float(eq.z << 16);
        pr[5] = a[5] * __uint_as_float(eq.z & 0xFFFF0000u);
        pr[6] = a[6] * __uint_as_float(eq.w << 16);
        pr[7] = a[7] * __uint_as_float(eq.w & 0xFFFF0000u);
        bf16* ob = out + (long)row * 128 + p * 16;
        *(uint4*)ob = make_uint4(pk2(a[0], a[1]), pk2(a[2], a[3]),
                                 pk2(a[4], a[5]), pk2(a[6], a[7]));
        *(uint4*)(ob + 8) = make_uint4(pk2(pr[0], pr[1]), pk2(pr[2], pr[3]),
                                       pk2(pr[4], pr[5]), pk2(pr[6], pr[7]));
    }
}

// ---------------- Y[M,64] = act(X16[M,64] @ W[64,64] + b) -> bf16 --------------
// MFMA version: mfma_f32_16x16x32_bf16, weights split bf16 hi+lo for fp32-like
// accuracy (weight error ~2^-17). Wt = W^T in LDS (B^T fragment layout, +8 pad).
// A frag: row = lane&15, k = 8*(lane>>4)+e (contiguous 16B per lane from X row).
// D frag: col = lane&15, row = 4*(lane>>4)+reg  [verified mapping].
template <int ACT>
__global__ __launch_bounds__(256) void k_gemm64(const bf16* __restrict__ X,
                                                const void* __restrict__ W,
                                                const void* __restrict__ b,
                                                bf16* __restrict__ Y, int M,
                                                const int* __restrict__ flag) {
    __shared__ bf16 WtH[64][72];
    __shared__ bf16 WtL[64][72];
    __shared__ float bl[64];
    int f = *flag;
    int tid = threadIdx.x;
    for (int idx = tid; idx < 4096; idx += 256) {
        int n = idx >> 6, kk = idx & 63;
        float v = ldf(W, (long)kk * 64 + n, f);
        bf16 h = __float2bfloat16(v);
        WtH[n][kk] = h;
        WtL[n][kk] = __float2bfloat16(v - __bfloat162float(h));
    }
    if (tid < 64) bl[tid] = ldf(b, tid, f);
    __syncthreads();

    int l  = tid & 63;
    int lr = l & 15;      // A row / D col within tile
    int lk = l >> 4;      // k sub-block / D row group

    bf16x8 bh[2][4], bb[2][4];
#pragma unroll
    for (int kt = 0; kt < 2; kt++)
#pragma unroll
        for (int ct = 0; ct < 4; ct++) {
            int n  = ct * 16 + lr;
            int ko = kt * 32 + lk * 8;
            bh[kt][ct] = *(const bf16x8*)&WtH[n][ko];
            bb[kt][ct] = *(const bf16x8*)&WtL[n][ko];
        }

    int nt  = M >> 4;                       // M is a multiple of 16
    int wid = blockIdx.x * 4 + (tid >> 6);
    int nw  = gridDim.x * 4;

    for (int t = wid; t < nt; t += nw) {
        const bf16* Ap = X + (long)(t * 16 + lr) * 64 + lk * 8;
        bf16x8 a[2];
#pragma unroll
        for (int kt = 0; kt < 2; kt++) a[kt] = *(const bf16x8*)(Ap + kt * 32);

        f32x4 acc[4];
#pragma unroll
        for (int ct = 0; ct < 4; ct++) {
            float bv = bl[ct * 16 + lr];
            acc[ct] = (f32x4){bv, bv, bv, bv};
        }
#pragma unroll
        for (int kt = 0; kt < 2; kt++)
#pragma unroll
            for (int ct = 0; ct < 4; ct++) {
                acc[ct] = __builtin_amdgcn_mfma_f32_16x16x32_bf16(a[kt], bh[kt][ct], acc[ct], 0, 0, 0);
                acc[ct] = __builtin_amdgcn_mfma_f32_16x16x32_bf16(a[kt], bb[kt][ct], acc[ct], 0, 0, 0);
            }

#pragma unroll
        for (int r = 0; r < 4; r++) {
            float v0 = acc[0][r], v1 = acc[1][r], v2 = acc[2][r], v3 = acc[3][r];
            if (ACT == 2) {
                v0 = fmaxf(v0, 0.0f); v1 = fmaxf(v1, 0.0f);
                v2 = fmaxf(v2, 0.0f); v3 = fmaxf(v3, 0.0f);
            } else {
                v0 = (v0 > 0.0f) ? v0 : (expf(v0) - 1.0f);
                v1 = (v1 > 0.0f) ? v1 : (expf(v1) - 1.0f);
                v2 = (v2 > 0.0f) ? v2 : (expf(v2) - 1.0f);
                v3 = (v3 > 0.0f) ? v3 : (expf(v3) - 1.0f);
            }
            long ob = (long)(t * 16 + lk * 4 + r) * 64 + lr;
            Y[ob]      = __float2bfloat16(v0);
            Y[ob + 16] = __float2bfloat16(v1);
            Y[ob + 32] = __float2bfloat16(v2);
            Y[ob + 48] = __float2bfloat16(v3);
        }
    }
}

// ---------------- fused NGCF layer + l2norm; ego bf16 updated IN PLACE --------
// MFMA K=128 bf16 GEMM on interleaved SP rows ([S8|P8]x8); Wcat = interleaved
// stack of Wgc/Wbi rows, transposed into LDS as B^T, split bf16 hi+lo.
// Epilogue: leaky-relu + row l2norm via shfl_xor 1/2/4/8 over the 16-lane
// column group (lane holds cols ct*16 + (lane&15), rows 4*(lane>>4)+r).
__global__ __launch_bounds__(256) void k_layer(const bf16* __restrict__ SP,
                                               bf16* __restrict__ E16,
                                               const void* __restrict__ Wgc,
                                               const void* __restrict__ bgc,
                                               const void* __restrict__ Wbi,
                                               const void* __restrict__ bbi,
                                               long woff, long boff,
                                               bf16* __restrict__ nm, int M,
                                               const int* __restrict__ flag) {
    __shared__ bf16 WtH[64][136];
    __shared__ bf16 WtL[64][136];
    __shared__ float bl[64];
    int f = *flag;
    int tid = threadIdx.x;
    // Wcat[16g+j] = W1[8g+j]  (j<8),  Wcat[16g+8+j] = W2[8g+j]  -- matches SP interleave
    for (int idx = tid; idx < 8192; idx += 256) {
        int n = idx >> 7, kk = idx & 127;
        int g = kk >> 4, j = kk & 15;
        float v = (j < 8) ? ldf(Wgc, woff + (long)(8 * g + j) * 64 + n, f)
                          : ldf(Wbi, woff + (long)(8 * g + j - 8) * 64 + n, f);
        bf16 h = __float2bfloat16(v);
        WtH[n][kk] = h;
        WtL[n][kk] = __float2bfloat16(v - __bfloat162float(h));
    }
    if (tid < 64) bl[tid] = ldf(bgc, boff + tid, f) + ldf(bbi, boff + tid, f);
    __syncthreads();

    int l  = tid & 63;
    int lr = l & 15;
    int lk = l >> 4;

    bf16x8 bh[4][4], bb[4][4];
#pragma unroll
    for (int kt = 0; kt < 4; kt++)
#pragma unroll
        for (int ct = 0; ct < 4; ct++) {
            int n  = ct * 16 + lr;
            int ko = kt * 32 + lk * 8;
            bh[kt][ct] = *(const bf16x8*)&WtH[n][ko];
            bb[kt][ct] = *(const bf16x8*)&WtL[n][ko];
        }

    int nt  = M >> 4;                 // 11250 for NTOT
    int wid = blockIdx.x * 4 + (tid >> 6);
    int nw  = gridDim.x * 4;

    for (int t = wid; t < nt; t += nw) {
        const bf16* Ap = SP + (long)(t * 16 + lr) * 128 + lk * 8;
        bf16x8 a[4];
#pragma unroll
        for (int kt = 0; kt < 4; kt++) a[kt] = *(const bf16x8*)(Ap + kt * 32);

        f32x4 acc[4];
#pragma unroll
        for (int ct = 0; ct < 4; ct++) {
            float bv = bl[ct * 16 + lr];
            acc[ct] = (f32x4){bv, bv, bv, bv};
        }
#pragma unroll
        for (int kt = 0; kt < 4; kt++)
#pragma unroll
            for (int ct = 0; ct < 4; ct++) {
                acc[ct] = __builtin_amdgcn_mfma_f32_16x16x32_bf16(a[kt], bh[kt][ct], acc[ct], 0, 0, 0);
                acc[ct] = __builtin_amdgcn_mfma_f32_16x16x32_bf16(a[kt], bb[kt][ct], acc[ct], 0, 0, 0);
            }

#pragma unroll
        for (int r = 0; r < 4; r++) {
            float v0 = acc[0][r], v1 = acc[1][r], v2 = acc[2][r], v3 = acc[3][r];
            v0 = (v0 > 0.0f) ? v0 : 0.2f * v0;
            v1 = (v1 > 0.0f) ? v1 : 0.2f * v1;
            v2 = (v2 > 0.0f) ? v2 : 0.2f * v2;
            v3 = (v3 > 0.0f) ? v3 : 0.2f * v3;
            float ss = v0 * v0 + v1 * v1 + v2 * v2 + v3 * v3;
            ss += __shfl_xor(ss, 1, 64);    // reduce over the 16-lane column group
            ss += __shfl_xor(ss, 2, 64);
            ss += __shfl_xor(ss, 4, 64);
            ss += __shfl_xor(ss, 8, 64);
            float sc2 = 1.0f / fmaxf(sqrtf(ss), 1e-12f);
            long ob = (long)(t * 16 + lk * 4 + r) * 64 + lr;
            E16[ob]      = __float2bfloat16(v0);
            E16[ob + 16] = __float2bfloat16(v1);
            E16[ob + 32] = __float2bfloat16(v2);
            E16[ob + 48] = __float2bfloat16(v3);
            nm[ob]       = __float2bfloat16(v0 * sc2);
            nm[ob + 16]  = __float2bfloat16(v1 * sc2);
            nm[ob + 32]  = __float2bfloat16(v2 * sc2);
            nm[ob + 48]  = __float2bfloat16(v3 * sc2);
        }
    }
}

// ---------------- final gather into output ----------------
__global__ __launch_bounds__(64) void k_gather(const int* __restrict__ users,
                                               const int* __restrict__ pos,
                                               const int* __restrict__ neg,
                                               const void* __restrict__ ue,
                                               const void* __restrict__ ie,
                                               const bf16* __restrict__ n1,
                                               const bf16* __restrict__ n2,
                                               const bf16* __restrict__ n3,
                                               const bf16* __restrict__ uh,
                                               const bf16* __restrict__ ih,
                                               void* __restrict__ out,
                                               const int* __restrict__ flag) {
    int f = *flag;
    int b = blockIdx.x;           // 0..12287: [users | pos | neg] x 4096
    int which = b >> 12;
    int s = b & 4095;
    int lane = threadIdx.x;       // 64
    long ebase, nbase;
    const void* e0;
    const bf16* hh;
    if (which == 0) {
        int r = users[s];
        e0 = ue; ebase = (long)r * 64;
        hh = uh + (long)r * 64;
        nbase = (long)r * 64;
    } else {
        int r = (which == 1) ? pos[s] : neg[s];
        e0 = ie; ebase = (long)r * 64;
        hh = ih + (long)r * 64;
        nbase = (long)(N_USER + r) * 64;
    }
    float o0 = ldf(e0, ebase + lane, f);
    float o1 = __bfloat162float(n1[nbase + lane]);
    float o2 = __bfloat162float(n2[nbase + lane]);
    float o3 = __bfloat162float(n3[nbase + lane]);
    float o4 = __bfloat162float(hh[lane]);
    long ob = (long)b * 320;
    if (f) {
        float* o = (float*)out + ob;
        o[lane] = o0; o[64 + lane] = o1; o[128 + lane] = o2;
        o[192 + lane] = o3; o[256 + lane] = o4;
    } else {
        bf16* o = (bf16*)out + ob;
        o[lane]       = __float2bfloat16(o0);
        o[64 + lane]  = __float2bfloat16(o1);
        o[128 + lane] = __float2bfloat16(o2);
        o[192 + lane] = __float2bfloat16(o3);
        o[256 + lane] = __float2bfloat16(o4);
    }
}

// host-side helper: two-level build of row-sorted packed records for one graph
static void build_graph(const int* rows, const int* cols, const void* vals,
                        int nnz, int nsb, int cap, int n_rows,
                        int* sbpos, uint2* recTmp, uint2* rec2,
                        int* rstart, int* rend,
                        const int* FLAG, hipStream_t stream) {
    k_initpos<<<1, 256, 0, stream>>>(sbpos, nsb, cap);
    k_part<<<(nnz + CHUNK - 1) / CHUNK, 256, 0, stream>>>(rows, cols, vals, recTmp, sbpos, nnz, FLAG);
    k_sortsb<<<nsb, 1024, 0, stream>>>(recTmp, rec2, rstart, rend, sbpos, cap, n_rows);
}

extern "C" void kernel_launch(void* const* d_in, const int* in_sizes, int n_in,
                              void* d_out, int out_size, void* d_ws, size_t ws_size,
                              hipStream_t stream) {
    const int* users = (const int*)d_in[0];
    const int* pos   = (const int*)d_in[1];
    const int* neg   = (const int*)d_in[2];
    const int* adj_r = (const int*)d_in[3];
    const int* adj_c = (const int*)d_in[4];
    const void* adj_v = d_in[5];
    const int* ug_r  = (const int*)d_in[6];
    const int* ug_c  = (const int*)d_in[7];
    const void* ug_v = d_in[8];
    const int* ig_r  = (const int*)d_in[9];
    const int* ig_c  = (const int*)d_in[10];
    const void* ig_v = d_in[11];
    const void* ue   = d_in[12];
    const void* ie   = d_in[13];
    const void* Wgc  = d_in[14];
    const void* bgc  = d_in[15];
    const void* Wbi  = d_in[16];
    const void* bbi  = d_in[17];
    const void* Wu0  = d_in[18];
    const void* bu0  = d_in[19];
    const void* Wu1  = d_in[20];
    const void* bu1  = d_in[21];
    const void* Wi0  = d_in[22];
    const void* bi0  = d_in[23];
    const void* Wi1  = d_in[24];
    const void* bi1  = d_in[25];

    char* ws = (char*)d_ws;
    int*   FLAG  = (int*)(ws + 0);                       // 256 B
    bf16*  SP16A = (bf16*)(ws + 256);                    // NTOT*128*2 = 46,080,000
    bf16*  S16T  = (bf16*)(ws + 46080256L);              // N_ITEM*64*2 = 15,360,000
    bf16*  ego16 = (bf16*)(ws + 61440256L);              // 23,040,000
    bf16*  UH    = (bf16*)(ws + 84480256L);              //  7,680,000
    bf16*  IH    = (bf16*)(ws + 92160256L);              // 15,360,000
    bf16*  NM1   = (bf16*)(ws + 107520256L);             // 23,040,000
    bf16*  NM2   = (bf16*)(ws + 130560256L);             // 23,040,000
    bf16*  NM3   = (bf16*)(ws + 153600256L);             // 23,040,000
    // T2 (bf16, <=15.36 MB) aliases NM2: dead before layer k=1 writes NM2
    bf16*  T2    = (bf16*)(ws + 130560256L);
    // recTmp aliases SP16A: builds finish before first adj spmm writes SP16A
    uint2* recTmp = (uint2*)(ws + 256);
    uint2* rec2A = (uint2*)(ws + 176640256L);            // 30,277,632
    uint2* rec2U = (uint2*)(ws + 206917888L);            //  8,355,840
    uint2* rec2I = (uint2*)(ws + 215273728L);            // 16,433,152
    int* rstartA = (int*)(ws + 231706880L);              //    720,000
    int* rendA   = (int*)(ws + 232426880L);              //    720,000
    int* rstartU = (int*)(ws + 233146880L);              //    240,000
    int* rendU   = (int*)(ws + 233386880L);              //    240,000
    int* rstartI = (int*)(ws + 233626880L);              //    480,000
    int* rendI   = (int*)(ws + 234106880L);              //    480,000
    int* sbpos   = (int*)(ws + 234586880L);              //      6,144
                                                         // end 234,593,024 (< 261,120,256 proven)

    k_detect<<<1, 64, 0, stream>>>(adj_v, FLAG);
    k_cast16<<<45000, 256, 0, stream>>>(ue, ie, ego16, FLAG);

    // ---- two-level build of row-sorted packed records (recTmp aliases SP16A) ----
    build_graph(ug_r,  ug_c,  ug_v,  NNZ_UG,  NSB_UG,  CAPU_SB, N_USER,
                sbpos, recTmp, rec2U, rstartU, rendU, FLAG, stream);
    build_graph(ig_r,  ig_c,  ig_v,  NNZ_IG,  NSB_IG,  CAPI_SB, N_ITEM,
                sbpos, recTmp, rec2I, rstartI, rendI, FLAG, stream);
    build_graph(adj_r, adj_c, adj_v, NNZ_ADJ, NSB_ADJ, CAPA_SB, NTOT,
                sbpos, recTmp, rec2A, rstartA, rendA, FLAG, stream);

    // ---- user MLP branch (bf16 S throughout) ----
    int gu = (N_USER / 16 + 7) / 8;     // ~2 row-tiles per wave
    int gi = (N_ITEM / 16 + 7) / 8;
    k_spmm_bf<1><<<(N_USER + 31) / 32, 256, 0, stream>>>(rstartU, rendU, rec2U, ego16, S16T, nullptr, N_USER);
    k_gemm64<1><<<gu, 256, 0, stream>>>(S16T, Wu0, bu0, T2, N_USER, FLAG);
    k_spmm_bf<1><<<(N_USER + 31) / 32, 256, 0, stream>>>(rstartU, rendU, rec2U, T2, S16T, nullptr, N_USER);
    k_gemm64<2><<<gu, 256, 0, stream>>>(S16T, Wu1, bu1, UH, N_USER, FLAG);

    // ---- item MLP branch ----
    const bf16* ego16I = ego16 + (size_t)N_USER * 64;
    k_spmm_bf<1><<<(N_ITEM + 31) / 32, 256, 0, stream>>>(rstartI, rendI, rec2I, ego16I, S16T, nullptr, N_ITEM);
    k_gemm64<1><<<gi, 256, 0, stream>>>(S16T, Wi0, bi0, T2, N_ITEM, FLAG);
    k_spmm_bf<1><<<(N_ITEM + 31) / 32, 256, 0, stream>>>(rstartI, rendI, rec2I, T2, S16T, nullptr, N_ITEM);
    k_gemm64<2><<<gi, 256, 0, stream>>>(S16T, Wi1, bi1, IH, N_ITEM, FLAG);

    // ---- 3 NGCF layers: spmm emits interleaved [S|P] bf16; layer = MFMA K=128 GEMM ----
    bf16* norms[3] = {NM1, NM2, NM3};
    for (int k = 0; k < 3; k++) {
        k_spmm_bf<2><<<(NTOT + 31) / 32, 256, 0, stream>>>(rstartA, rendA, rec2A, ego16, SP16A, ego16, NTOT);
        // 704 blocks * 4 waves = 2816 waves -> ~4 row-tiles each of 11250
        k_layer<<<704, 256, 0, stream>>>(SP16A, ego16, Wgc, bgc, Wbi, bbi,
                                         (long)k * 4096, (long)k * 64,
                                         norms[k], NTOT, FLAG);
    }

    // ---- output gather ----
    k_gather<<<12288, 64, 0, stream>>>(users, pos, neg, ue, ie, NM1, NM2, NM3, UH, IH,
                                       d_out, FLAG);
}